// Round 2
// baseline (602.210 us; speedup 1.0000x reference)
//
#include <hip/hip_runtime.h>
#include <cstdint>
#include <cstddef>

typedef _Float16 f16_t;
typedef f16_t f16x8 __attribute__((ext_vector_type(8)));
typedef float  floatx4 __attribute__((ext_vector_type(4)));

#define S_LEN 2048
#define DIM_  4096
#define NH    32
#define NKV   8
#define HD    128
#define KV_DIM (NKV * HD)        // 1024
#define QLD   (DIM_ + 2 * KV_DIM) // 6144: fused QKV row stride

// round-to-nearest-even onto the bf16 grid, result stays fp32.
// (reference is computed from bf16-rounded inputs; we must share its grid.)
__device__ __forceinline__ float bf16r(float x) {
    uint32_t u = __float_as_uint(x);
    u = (u + 0x7fffu + ((u >> 16) & 1u)) & 0xffff0000u;
    return __uint_as_float(u);
}

// async global->LDS, 16B per lane (lane-contiguous LDS dest required)
__device__ __forceinline__ void gload_lds16(const f16_t* g, f16_t* l) {
    __builtin_amdgcn_global_load_lds(
        (const __attribute__((address_space(1))) void*)g,
        (__attribute__((address_space(3))) void*)l, 16, 0, 0);
}

// ---------------------------------------------------------------------------
// fp32 -> bf16-grid -> fp16 (lossless embed), 8 elements / thread
// ---------------------------------------------------------------------------
__global__ void f32_to_f16_kernel(const float* __restrict__ in,
                                  f16_t* __restrict__ out, int n) {
    int i = (blockIdx.x * blockDim.x + threadIdx.x) * 8;
    if (i >= n) return;
    float4 a = *(const float4*)(in + i);
    float4 b = *(const float4*)(in + i + 4);
    f16x8 o;
    o[0] = (f16_t)bf16r(a.x); o[1] = (f16_t)bf16r(a.y);
    o[2] = (f16_t)bf16r(a.z); o[3] = (f16_t)bf16r(a.w);
    o[4] = (f16_t)bf16r(b.x); o[5] = (f16_t)bf16r(b.y);
    o[6] = (f16_t)bf16r(b.z); o[7] = (f16_t)bf16r(b.w);
    *(f16x8*)(out + i) = o;
}

// ---------------------------------------------------------------------------
// all 4 weight transposes in ONE kernel (fp32 -> bf16 grid -> fp16).
// wq[4096][4096]->wqkvT rows 0..4095 ; wk[4096][1024]->rows 4096..5119 ;
// wv[4096][1024]->rows 5120..6143 ; wo[4096][4096]->woT.  out row stride 4096.
// block (32,8), 1-D grid of 40960 blocks.
// ---------------------------------------------------------------------------
__global__ void transpose_weights_kernel(const float* __restrict__ wq,
                                         const float* __restrict__ wk,
                                         const float* __restrict__ wv,
                                         const float* __restrict__ wo,
                                         f16_t* __restrict__ wqkvT,
                                         f16_t* __restrict__ woT) {
    __shared__ float tile[32][33];
    int bid = blockIdx.x;
    const float* in; f16_t* out; int C;
    if (bid < 16384)      { in = wq; out = wqkvT;                          C = 4096; }
    else if (bid < 20480) { bid -= 16384; in = wk; out = wqkvT + (size_t)4096 * 4096; C = 1024; }
    else if (bid < 24576) { bid -= 20480; in = wv; out = wqkvT + (size_t)5120 * 4096; C = 1024; }
    else                  { bid -= 24576; in = wo; out = woT;              C = 4096; }
    int gpr = C / 32;
    int bx = (bid % gpr) * 32;   // col offset in input
    int by = (bid / gpr) * 32;   // row offset in input (K dim, 4096)
    int tx = threadIdx.x, ty = threadIdx.y;
#pragma unroll
    for (int i = 0; i < 4; i++) {
        int r = ty + i * 8;
        tile[r][tx] = in[(size_t)(by + r) * C + bx + tx];
    }
    __syncthreads();
#pragma unroll
    for (int i = 0; i < 4; i++) {
        int r = ty + i * 8;
        out[(size_t)(bx + r) * 4096 + by + tx] = (f16_t)bf16r(tile[tx][r]);
    }
}

// ---------------------------------------------------------------------------
// generic fp16 transpose with strides: in [R][C] (ldi) -> out [C][R] (ldo)
// (pure passthrough: f16 -> f32 -> f16 is exact)
// ---------------------------------------------------------------------------
__global__ void transpose_f16_kernel(const f16_t* __restrict__ in,
                                     f16_t* __restrict__ out,
                                     int ldi, int ldo) {
    __shared__ float tile[32][33];
    int bx = blockIdx.x * 32;  // C offset
    int by = blockIdx.y * 32;  // R offset
    int tx = threadIdx.x, ty = threadIdx.y;
#pragma unroll
    for (int i = 0; i < 4; i++) {
        int r = ty + i * 8;
        tile[r][tx] = (float)in[(size_t)(by + r) * ldi + bx + tx];
    }
    __syncthreads();
#pragma unroll
    for (int i = 0; i < 4; i++) {
        int r = ty + i * 8;
        out[(size_t)(bx + r) * ldo + by + tx] = (f16_t)tile[tx][r];
    }
}

// ---------------------------------------------------------------------------
// fp16 GEMM (m97 structure): C[M][N] = A[M][K] @ BT[N][K]^T
// 128x128 tile, BK=32, 4 waves, global_load_lds width-16 staging (no pad).
// ---------------------------------------------------------------------------
template <typename OutT>
__global__ __launch_bounds__(256) void gemm_bt_kernel(
        const f16_t* __restrict__ A, const f16_t* __restrict__ BT,
        OutT* __restrict__ C, int M, int N, int K) {
    constexpr int BM = 128, BN = 128, BK = 32;
    __shared__ f16_t As[BM * BK];
    __shared__ f16_t Bs[BN * BK];

    const int tid  = threadIdx.x;
    const int lane = tid & 63;
    const int wave = tid >> 6;
    const int wm = (wave >> 1) * 64;
    const int wn = (wave & 1) * 64;
    const int quad = lane >> 4;
    const int l16  = lane & 15;
    const int m0 = blockIdx.y * BM;
    const int n0 = blockIdx.x * BN;

    const int sr  = tid >> 2;        // 0..63
    const int sc8 = (tid & 3) * 8;   // 0,8,16,24
    const f16_t* Ag = A  + (size_t)(m0 + sr) * K + sc8;
    const f16_t* Bg = BT + (size_t)(n0 + sr) * K + sc8;
    f16_t* AsW0 = &As[sr * BK + sc8];
    f16_t* AsW1 = &As[(sr + 64) * BK + sc8];
    f16_t* BsW0 = &Bs[sr * BK + sc8];
    f16_t* BsW1 = &Bs[(sr + 64) * BK + sc8];

    floatx4 acc[4][4] = {};

    for (int k0 = 0; k0 < K; k0 += BK) {
        gload_lds16(Ag + k0, AsW0);
        gload_lds16(Ag + k0 + (size_t)64 * K, AsW1);
        gload_lds16(Bg + k0, BsW0);
        gload_lds16(Bg + k0 + (size_t)64 * K, BsW1);
        asm volatile("s_waitcnt vmcnt(0)" ::: "memory");
        __syncthreads();

        f16x8 af[4], bfr[4];
#pragma unroll
        for (int mt = 0; mt < 4; mt++)
            af[mt] = *(const f16x8*)&As[(wm + mt * 16 + l16) * BK + quad * 8];
#pragma unroll
        for (int nt = 0; nt < 4; nt++)
            bfr[nt] = *(const f16x8*)&Bs[(wn + nt * 16 + l16) * BK + quad * 8];
#pragma unroll
        for (int mt = 0; mt < 4; mt++)
#pragma unroll
            for (int nt = 0; nt < 4; nt++)
                acc[mt][nt] = __builtin_amdgcn_mfma_f32_16x16x32_f16(
                    af[mt], bfr[nt], acc[mt][nt], 0, 0, 0);
        __syncthreads();
    }

#pragma unroll
    for (int mt = 0; mt < 4; mt++)
#pragma unroll
        for (int nt = 0; nt < 4; nt++)
#pragma unroll
            for (int rg = 0; rg < 4; rg++) {
                int row = m0 + wm + mt * 16 + quad * 4 + rg;
                int col = n0 + wn + nt * 16 + l16;
                C[(size_t)row * N + col] = (OutT)acc[mt][nt][rg];
            }
}

// ---------------------------------------------------------------------------
// Flash attention, causal, RoPE fused.
//  QKV [S][6144] fp16 (cols: Q 0..4095 | K 4096..5119 | V 5120..6143), un-roped
//  Vt  [NKV][HD][S] fp16
//  O   [S][4096] fp16
// 512 thr = 8 waves; BQ=128 (16 rows/wave); K-tiles of 64.
// 1-D grid of 512: h = bid&31, g = bid>>5, qt = g<8 ? g : 23-g (pair-balanced)
// cos/sin are rounded to the bf16 grid (reference shares that grid), math fp32.
// ---------------------------------------------------------------------------
__global__ __launch_bounds__(512) void attn_kernel(
        const f16_t* __restrict__ QKV, const f16_t* __restrict__ Vt,
        const float* __restrict__ fcos, const float* __restrict__ fsin,
        f16_t* __restrict__ O) {
    constexpr int BK = 64;
    constexpr int KS = HD + 8;   // 136 elem stride: 272B, bank-stride 4 -> conflict-free
    constexpr int VS = BK + 8;   // 72  elem stride: 144B
    __shared__ f16_t Ks[BK][KS];        // 17408 B
    __shared__ f16_t Vs[HD][VS];        // 18432 B
    __shared__ f16_t Ps[8][16][72];     // 18432 B  (wave-private rows)

    const int tid  = threadIdx.x;
    const int lane = tid & 63;
    const int wave = tid >> 6;
    const int quad = lane >> 4;
    const int l16  = lane & 15;

    const int bid = blockIdx.x;
    const int h   = bid & 31;
    const int g   = bid >> 5;
    const int qt  = (g < 8) ? g : 23 - g;
    const int q0  = qt * 128;
    const int hkv = h >> 2;

    // ---- Q fragments with in-register RoPE ----
    const int qrow = q0 + wave * 16 + l16;
    f16x8 qf[4];
    {
        const f16_t* Qg = QKV + (size_t)qrow * QLD + h * HD;
        const float* cr = fcos + qrow * 64;
        const float* sr = fsin + qrow * 64;
#pragma unroll
        for (int c = 0; c < 4; c++) {
            f16x8 v = *(const f16x8*)(Qg + c * 32 + quad * 8);
#pragma unroll
            for (int u = 0; u < 4; u++) {
                int fi = c * 16 + quad * 4 + u;
                float cc = bf16r(cr[fi]), ss = bf16r(sr[fi]);
                float re = (float)v[2 * u], im = (float)v[2 * u + 1];
                v[2 * u]     = (f16_t)(re * cc - im * ss);
                v[2 * u + 1] = (f16_t)(re * ss + im * cc);
            }
            qf[c] = v;
        }
    }

    floatx4 o_acc[8] = {};
    float m_run[4], l_run[4];
#pragma unroll
    for (int i = 0; i < 4; i++) { m_run[i] = -1e30f; l_run[i] = 0.f; }
    const float scale = 0.08838834764831845f;  // 1/sqrt(128)

    const int q_lo = q0 + wave * 16;
    const int q_hi = q_lo + 15;
    const int ntiles = q0 / BK + 2;

    // staging index precompute
    const int krr = tid >> 4;           // 0..31
    const int kcc = (tid & 15) * 8;     // 0..120
    const int vr  = tid >> 3;           // 0..63
    const int vc  = (tid & 7) * 8;      // 0..56
    const f16_t* Vg = Vt + (size_t)hkv * HD * S_LEN;

    for (int t = 0; t < ntiles; t++) {
        const int k0 = t * BK;

        // ---- stage K tile (with fused RoPE) + V^T tile ----
#pragma unroll
        for (int p = 0; p < 2; p++) {
            int krow = k0 + p * 32 + krr;
            f16x8 v = *(const f16x8*)(QKV + (size_t)krow * QLD + DIM_ + hkv * HD + kcc);
            const float* cr = fcos + krow * 64;
            const float* sr = fsin + krow * 64;
#pragma unroll
            for (int u = 0; u < 4; u++) {
                int fi = kcc / 2 + u;
                float cc = bf16r(cr[fi]), ss = bf16r(sr[fi]);
                float re = (float)v[2 * u], im = (float)v[2 * u + 1];
                v[2 * u]     = (f16_t)(re * cc - im * ss);
                v[2 * u + 1] = (f16_t)(re * ss + im * cc);
            }
            *(f16x8*)&Ks[p * 32 + krr][kcc] = v;
        }
#pragma unroll
        for (int p = 0; p < 2; p++)
            *(f16x8*)&Vs[p * 64 + vr][vc] =
                *(const f16x8*)(Vg + (size_t)(p * 64 + vr) * S_LEN + k0 + vc);
        __syncthreads();

        if (k0 <= q_hi) {  // tile not fully masked for this wave
            // ---- S = Q K^T (16 x 64) ----
            floatx4 sc4[4] = {};
#pragma unroll
            for (int nt = 0; nt < 4; nt++)
#pragma unroll
                for (int ks = 0; ks < 4; ks++) {
                    f16x8 kf = *(const f16x8*)&Ks[nt * 16 + l16][ks * 32 + quad * 8];
                    sc4[nt] = __builtin_amdgcn_mfma_f32_16x16x32_f16(qf[ks], kf, sc4[nt], 0, 0, 0);
                }

            const bool needmask = (k0 + BK - 1) > q_lo;
#pragma unroll
            for (int nt = 0; nt < 4; nt++)
#pragma unroll
                for (int rg = 0; rg < 4; rg++) {
                    float s = sc4[nt][rg] * scale;
                    if (needmask) {
                        int qg = q_lo + quad * 4 + rg;
                        int kg = k0 + nt * 16 + l16;
                        if (kg > qg) s = -1e30f;
                    }
                    sc4[nt][rg] = s;
                }

            // ---- online softmax (rows = quad*4+rg, cols across l16 x nt) ----
            float alpha[4];
#pragma unroll
            for (int rg = 0; rg < 4; rg++) {
                float m = fmaxf(fmaxf(sc4[0][rg], sc4[1][rg]), fmaxf(sc4[2][rg], sc4[3][rg]));
#pragma unroll
                for (int off = 8; off >= 1; off >>= 1)
                    m = fmaxf(m, __shfl_xor(m, off, 64));
                float mn = fmaxf(m_run[rg], m);
                alpha[rg] = __expf(m_run[rg] - mn);
                m_run[rg] = mn;
            }
            float rsum[4] = {0.f, 0.f, 0.f, 0.f};
#pragma unroll
            for (int nt = 0; nt < 4; nt++)
#pragma unroll
                for (int rg = 0; rg < 4; rg++) {
                    float p = __expf(sc4[nt][rg] - m_run[rg]);
                    sc4[nt][rg] = p;
                    rsum[rg] += p;
                }
#pragma unroll
            for (int rg = 0; rg < 4; rg++) {
                float s = rsum[rg];
#pragma unroll
                for (int off = 8; off >= 1; off >>= 1)
                    s += __shfl_xor(s, off, 64);
                l_run[rg] = l_run[rg] * alpha[rg] + s;
            }
#pragma unroll
            for (int dt = 0; dt < 8; dt++)
#pragma unroll
                for (int rg = 0; rg < 4; rg++) o_acc[dt][rg] *= alpha[rg];

            // ---- P: C-layout -> LDS -> A-layout (wave-private, no barrier) ----
#pragma unroll
            for (int nt = 0; nt < 4; nt++)
#pragma unroll
                for (int rg = 0; rg < 4; rg++)
                    Ps[wave][quad * 4 + rg][nt * 16 + l16] = (f16_t)sc4[nt][rg];
            asm volatile("s_waitcnt lgkmcnt(0)" ::: "memory");
            __builtin_amdgcn_sched_barrier(0);

            // ---- O += P V ----
#pragma unroll
            for (int ks = 0; ks < 2; ks++) {
                f16x8 pf = *(const f16x8*)&Ps[wave][l16][ks * 32 + quad * 8];
#pragma unroll
                for (int dt = 0; dt < 8; dt++) {
                    f16x8 vf = *(const f16x8*)&Vs[dt * 16 + l16][ks * 32 + quad * 8];
                    o_acc[dt] = __builtin_amdgcn_mfma_f32_16x16x32_f16(pf, vf, o_acc[dt], 0, 0, 0);
                }
            }
        }
        __syncthreads();
    }

    // ---- epilogue ----
#pragma unroll
    for (int rg = 0; rg < 4; rg++) {
        float inv_l = 1.0f / l_run[rg];
#pragma unroll
        for (int dt = 0; dt < 8; dt++) {
            int row = q0 + wave * 16 + quad * 4 + rg;
            int col = h * HD + dt * 16 + l16;
            O[(size_t)row * (NH * HD) + col] = (f16_t)(o_acc[dt][rg] * inv_l);
        }
    }
}

// ---------------------------------------------------------------------------
// launch
// ---------------------------------------------------------------------------
extern "C" void kernel_launch(void* const* d_in, const int* in_sizes, int n_in,
                              void* d_out, int out_size, void* d_ws, size_t ws_size,
                              hipStream_t stream) {
    const float* x    = (const float*)d_in[0];
    const float* wq   = (const float*)d_in[1];
    const float* wk   = (const float*)d_in[2];
    const float* wv   = (const float*)d_in[3];
    const float* wo   = (const float*)d_in[4];
    const float* fcos = (const float*)d_in[5];
    const float* fsin = (const float*)d_in[6];
    float* out = (float*)d_out;

    char* ws = (char*)d_ws;
    constexpr size_t MB = 1024 * 1024;
    f16_t* xb    = (f16_t*)(ws + 0 * MB);     // 16 MB  [2048][4096]
    f16_t* wqkvT = (f16_t*)(ws + 16 * MB);    // 48 MB  [6144][4096]
    f16_t* woT   = (f16_t*)(ws + 64 * MB);    // 32 MB  [4096][4096]
    f16_t* QKVb  = (f16_t*)(ws + 96 * MB);    // 24 MB  [2048][6144]
    f16_t* Vt    = (f16_t*)(ws + 120 * MB);   //  4 MB  [8][128][2048]
    f16_t* attnb = (f16_t*)(ws + 124 * MB);   // 16 MB  [2048][4096]

    // 1. convert x; transpose-convert all weights (one kernel) — both onto bf16 grid
    f32_to_f16_kernel<<<S_LEN * DIM_ / 8 / 256, 256, 0, stream>>>(x, xb, S_LEN * DIM_);
    transpose_weights_kernel<<<40960, dim3(32, 8), 0, stream>>>(wq, wk, wv, wo, wqkvT, woT);

    // 2. fused QKV projection: [2048][4096] x [6144][4096]^T -> [2048][6144]
    gemm_bt_kernel<f16_t><<<dim3(QLD / 128, S_LEN / 128), 256, 0, stream>>>(
        xb, wqkvT, QKVb, S_LEN, QLD, DIM_);

    // 3. V^T: QKVb cols 5120..6143 -> Vt [8][128][2048]
    transpose_f16_kernel<<<dim3(KV_DIM / 32, S_LEN / 32), dim3(32, 8), 0, stream>>>(
        QKVb + 5120, Vt, QLD, S_LEN);

    // 4. causal flash attention (RoPE fused)
    attn_kernel<<<512, 512, 0, stream>>>(QKVb, Vt, fcos, fsin, attnb);

    // 5. output projection (fp32 out)
    gemm_bt_kernel<float><<<dim3(DIM_ / 128, S_LEN / 128), 256, 0, stream>>>(
        attnb, woT, out, S_LEN, DIM_, DIM_);
}

// Round 3
// 561.904 us; speedup vs baseline: 1.0717x; 1.0717x over previous
//
#include <hip/hip_runtime.h>
#include <cstdint>
#include <cstddef>

typedef _Float16 f16_t;
typedef f16_t f16x8 __attribute__((ext_vector_type(8)));
typedef float  floatx4 __attribute__((ext_vector_type(4)));

#define S_LEN 2048
#define DIM_  4096
#define NH    32
#define NKV   8
#define HD    128
#define KV_DIM (NKV * HD)        // 1024
#define QLD   (DIM_ + 2 * KV_DIM) // 6144: fused QKV row stride

// round-to-nearest-even onto the bf16 grid, result stays fp32.
// (reference is computed from bf16-rounded inputs; we must share its grid.)
__device__ __forceinline__ float bf16r(float x) {
    uint32_t u = __float_as_uint(x);
    u = (u + 0x7fffu + ((u >> 16) & 1u)) & 0xffff0000u;
    return __uint_as_float(u);
}

// async global->LDS, 16B per lane (lane-contiguous LDS dest required)
__device__ __forceinline__ void gload_lds16(const f16_t* g, f16_t* l) {
    __builtin_amdgcn_global_load_lds(
        (const __attribute__((address_space(1))) void*)g,
        (__attribute__((address_space(3))) void*)l, 16, 0, 0);
}

// ---------------------------------------------------------------------------
// fp32 -> bf16-grid -> fp16 (lossless embed), 8 elements / thread
// ---------------------------------------------------------------------------
__global__ void f32_to_f16_kernel(const float* __restrict__ in,
                                  f16_t* __restrict__ out, int n) {
    int i = (blockIdx.x * blockDim.x + threadIdx.x) * 8;
    if (i >= n) return;
    float4 a = *(const float4*)(in + i);
    float4 b = *(const float4*)(in + i + 4);
    f16x8 o;
    o[0] = (f16_t)bf16r(a.x); o[1] = (f16_t)bf16r(a.y);
    o[2] = (f16_t)bf16r(a.z); o[3] = (f16_t)bf16r(a.w);
    o[4] = (f16_t)bf16r(b.x); o[5] = (f16_t)bf16r(b.y);
    o[6] = (f16_t)bf16r(b.z); o[7] = (f16_t)bf16r(b.w);
    *(f16x8*)(out + i) = o;
}

// ---------------------------------------------------------------------------
// all 4 weight transposes in ONE kernel (fp32 -> bf16 grid -> fp16).
// ---------------------------------------------------------------------------
__global__ void transpose_weights_kernel(const float* __restrict__ wq,
                                         const float* __restrict__ wk,
                                         const float* __restrict__ wv,
                                         const float* __restrict__ wo,
                                         f16_t* __restrict__ wqkvT,
                                         f16_t* __restrict__ woT) {
    __shared__ float tile[32][33];
    int bid = blockIdx.x;
    const float* in; f16_t* out; int C;
    if (bid < 16384)      { in = wq; out = wqkvT;                          C = 4096; }
    else if (bid < 20480) { bid -= 16384; in = wk; out = wqkvT + (size_t)4096 * 4096; C = 1024; }
    else if (bid < 24576) { bid -= 20480; in = wv; out = wqkvT + (size_t)5120 * 4096; C = 1024; }
    else                  { bid -= 24576; in = wo; out = woT;              C = 4096; }
    int gpr = C / 32;
    int bx = (bid % gpr) * 32;   // col offset in input
    int by = (bid / gpr) * 32;   // row offset in input (K dim, 4096)
    int tx = threadIdx.x, ty = threadIdx.y;
#pragma unroll
    for (int i = 0; i < 4; i++) {
        int r = ty + i * 8;
        tile[r][tx] = in[(size_t)(by + r) * C + bx + tx];
    }
    __syncthreads();
#pragma unroll
    for (int i = 0; i < 4; i++) {
        int r = ty + i * 8;
        out[(size_t)(bx + r) * 4096 + by + tx] = (f16_t)bf16r(tile[tx][r]);
    }
}

// ---------------------------------------------------------------------------
// generic fp16 transpose with strides: in [R][C] (ldi) -> out [C][R] (ldo)
// ---------------------------------------------------------------------------
__global__ void transpose_f16_kernel(const f16_t* __restrict__ in,
                                     f16_t* __restrict__ out,
                                     int ldi, int ldo) {
    __shared__ float tile[32][33];
    int bx = blockIdx.x * 32;  // C offset
    int by = blockIdx.y * 32;  // R offset
    int tx = threadIdx.x, ty = threadIdx.y;
#pragma unroll
    for (int i = 0; i < 4; i++) {
        int r = ty + i * 8;
        tile[r][tx] = (float)in[(size_t)(by + r) * ldi + bx + tx];
    }
    __syncthreads();
#pragma unroll
    for (int i = 0; i < 4; i++) {
        int r = ty + i * 8;
        out[(size_t)(bx + r) * ldo + by + tx] = (f16_t)tile[tx][r];
    }
}

// ---------------------------------------------------------------------------
// Deep-pipelined fp16 GEMM: C[M][N] = A[M][K] @ BT[N][K]^T
// BMxBN tile, BK=32, 8 waves (512 thr), TRIPLE-buffered LDS, prefetch
// distance 2, counted vmcnt (never 0 in steady state), T2 XOR-swizzle,
// XCD-chunked block swizzle (each XCD owns one M-row of tiles).
//
// Schedule per iter t (tile t in buf t%3):
//   STAGE(t+2 -> buf (t+2)%3)            // gload_lds, joins vmcnt queue
//   ds_read frags from buf t%3           // safe: drained at iter t-1 + barrier
//   lgkmcnt(0); sched_barrier; MFMA (setprio 1)
//   vmcnt(LOADS)                         // drains tile t+1; t+2 stays in flight
//   s_barrier (raw: no implicit vmcnt(0) drain)
// Buffer-overwrite safety: buf[(t+2)%3] == buf[(t-1)%3], last read at iter
// t-1 and completed before iter t-1's lgkmcnt(0)+barrier.
//
// Swizzle (both-sides rule): logical byte L <-> lds byte L ^ (((L>>7)&3)<<4)
// (involution; bits 7+ untouched). Staging uses inverse-swizzled GLOBAL
// source with linear LDS dest (global_load_lds constraint); ds_read applies
// the same XOR -> 16 lanes of a quad spread 2 per bank-group (free).
// ---------------------------------------------------------------------------
template <int BM, int BN, typename OutT>
__global__ __launch_bounds__(512) void gemm_pipe_kernel(
        const f16_t* __restrict__ A, const f16_t* __restrict__ BT,
        OutT* __restrict__ C, int M, int N, int K, int nbx) {
    constexpr int BK = 32;
    constexpr int WN = BN / 64;          // waves along N (4 or 2)
    constexpr int WM = 8 / WN;           // waves along M (2 or 4)
    constexpr int MT = BM / WM / 16;     // 16-row frags per wave (8 or 4)
    constexpr int NT = 4;                // 64/16
    constexpr int ABY = BM * BK * 2;     // A tile bytes (16K or 16K)
    constexpr int BBY = BN * BK * 2;     // B tile bytes (16K or 8K)
    constexpr int AISS = ABY / 8192;     // collective 8KB issues
    constexpr int BISS = BBY / 8192;
    constexpr int LOADS = AISS + BISS;   // gloads per thread per tile (4 or 3)
    constexpr int BUF_EL = (ABY + BBY) / 2;

    __shared__ f16_t lds[3 * BUF_EL];    // 96 KB or 72 KB

    const int tid  = threadIdx.x;
    const int lane = tid & 63;
    const int wave = tid >> 6;
    const int quad = lane >> 4;
    const int l16  = lane & 15;
    const int wn = (wave % WN) * 64;
    const int wm = (wave / WN) * (BM / WM);

    // bijective XCD swizzle: nwg % 8 == 0 for both configs
    const int nwg = gridDim.x;
    const int swz = (blockIdx.x & 7) * (nwg >> 3) + (blockIdx.x >> 3);
    const int m0 = (swz / nbx) * BM;
    const int n0 = (swz % nbx) * BN;

    const f16_t* Arow = A  + (size_t)m0 * K;
    const f16_t* Brow = BT + (size_t)n0 * K;
    const int nt_tiles = K / BK;

    floatx4 acc[MT][NT] = {};

    auto stage = [&](int t, int q) {
        const int k0 = t * BK;
        f16_t* LdA = lds + q * BUF_EL;
#pragma unroll
        for (int j = 0; j < AISS; j++) {
            int Lb  = j * 8192 + tid * 16;                   // linear LDS byte
            int row = Lb >> 6;                               // /64B per row
            int cb  = (Lb & 48) ^ (((Lb >> 7) & 3) << 4);    // inverse-swz col
            gload_lds16(Arow + (size_t)row * K + k0 + (cb >> 1), LdA + (Lb >> 1));
        }
        f16_t* LdB = lds + q * BUF_EL + ABY / 2;
#pragma unroll
        for (int j = 0; j < BISS; j++) {
            int Lb  = j * 8192 + tid * 16;
            int row = Lb >> 6;
            int cb  = (Lb & 48) ^ (((Lb >> 7) & 3) << 4);
            gload_lds16(Brow + (size_t)row * K + k0 + (cb >> 1), LdB + (Lb >> 1));
        }
    };

    // prologue: tiles 0,1 staged; drain tile 0 only (tile 1 stays in flight)
    stage(0, 0);
    stage(1, 1);
    if constexpr (LOADS == 4) asm volatile("s_waitcnt vmcnt(4)" ::: "memory");
    else                      asm volatile("s_waitcnt vmcnt(3)" ::: "memory");
    __builtin_amdgcn_s_barrier();
    __builtin_amdgcn_sched_barrier(0);

    for (int t = 0; t < nt_tiles; ++t) {
        const int cur = t % 3;
        const bool pre = (t + 2 < nt_tiles);
        if (pre) stage(t + 2, (t + 2) % 3);

        const f16_t* Ab = lds + cur * BUF_EL;
        const f16_t* Bb = Ab + ABY / 2;
        f16x8 af[MT], bf[NT];
#pragma unroll
        for (int mt = 0; mt < MT; mt++) {
            int r  = wm + mt * 16 + l16;
            int cb = (quad * 16) ^ (((r >> 1) & 3) << 4);
            af[mt] = *(const f16x8*)(Ab + r * 32 + (cb >> 1));
        }
#pragma unroll
        for (int nt = 0; nt < NT; nt++) {
            int r  = wn + nt * 16 + l16;
            int cb = (quad * 16) ^ (((r >> 1) & 3) << 4);
            bf[nt] = *(const f16x8*)(Bb + r * 32 + (cb >> 1));
        }
        asm volatile("s_waitcnt lgkmcnt(0)" ::: "memory");
        __builtin_amdgcn_sched_barrier(0);
        __builtin_amdgcn_s_setprio(1);
#pragma unroll
        for (int mt = 0; mt < MT; mt++)
#pragma unroll
            for (int nt = 0; nt < NT; nt++)
                acc[mt][nt] = __builtin_amdgcn_mfma_f32_16x16x32_f16(
                    af[mt], bf[nt], acc[mt][nt], 0, 0, 0);
        __builtin_amdgcn_s_setprio(0);
        if (pre) {
            if constexpr (LOADS == 4) asm volatile("s_waitcnt vmcnt(4)" ::: "memory");
            else                      asm volatile("s_waitcnt vmcnt(3)" ::: "memory");
        } else {
            asm volatile("s_waitcnt vmcnt(0)" ::: "memory");
        }
        __builtin_amdgcn_s_barrier();
        __builtin_amdgcn_sched_barrier(0);
    }

#pragma unroll
    for (int mt = 0; mt < MT; mt++)
#pragma unroll
        for (int nt = 0; nt < NT; nt++)
#pragma unroll
            for (int rg = 0; rg < 4; rg++) {
                int row = m0 + wm + mt * 16 + quad * 4 + rg;
                int col = n0 + wn + nt * 16 + l16;
                C[(size_t)row * N + col] = (OutT)acc[mt][nt][rg];
            }
}

// ---------------------------------------------------------------------------
// Flash attention, causal, RoPE fused (unchanged from passing round).
// ---------------------------------------------------------------------------
__global__ __launch_bounds__(512) void attn_kernel(
        const f16_t* __restrict__ QKV, const f16_t* __restrict__ Vt,
        const float* __restrict__ fcos, const float* __restrict__ fsin,
        f16_t* __restrict__ O) {
    constexpr int BK = 64;
    constexpr int KS = HD + 8;   // 136 elem stride: conflict-free
    constexpr int VS = BK + 8;   // 72  elem stride
    __shared__ f16_t Ks[BK][KS];
    __shared__ f16_t Vs[HD][VS];
    __shared__ f16_t Ps[8][16][72];

    const int tid  = threadIdx.x;
    const int lane = tid & 63;
    const int wave = tid >> 6;
    const int quad = lane >> 4;
    const int l16  = lane & 15;

    const int bid = blockIdx.x;
    const int h   = bid & 31;
    const int g   = bid >> 5;
    const int qt  = (g < 8) ? g : 23 - g;
    const int q0  = qt * 128;
    const int hkv = h >> 2;

    const int qrow = q0 + wave * 16 + l16;
    f16x8 qf[4];
    {
        const f16_t* Qg = QKV + (size_t)qrow * QLD + h * HD;
        const float* cr = fcos + qrow * 64;
        const float* sr = fsin + qrow * 64;
#pragma unroll
        for (int c = 0; c < 4; c++) {
            f16x8 v = *(const f16x8*)(Qg + c * 32 + quad * 8);
#pragma unroll
            for (int u = 0; u < 4; u++) {
                int fi = c * 16 + quad * 4 + u;
                float cc = bf16r(cr[fi]), ss = bf16r(sr[fi]);
                float re = (float)v[2 * u], im = (float)v[2 * u + 1];
                v[2 * u]     = (f16_t)(re * cc - im * ss);
                v[2 * u + 1] = (f16_t)(re * ss + im * cc);
            }
            qf[c] = v;
        }
    }

    floatx4 o_acc[8] = {};
    float m_run[4], l_run[4];
#pragma unroll
    for (int i = 0; i < 4; i++) { m_run[i] = -1e30f; l_run[i] = 0.f; }
    const float scale = 0.08838834764831845f;

    const int q_lo = q0 + wave * 16;
    const int q_hi = q_lo + 15;
    const int ntiles = q0 / BK + 2;

    const int krr = tid >> 4;
    const int kcc = (tid & 15) * 8;
    const int vr  = tid >> 3;
    const int vc  = (tid & 7) * 8;
    const f16_t* Vg = Vt + (size_t)hkv * HD * S_LEN;

    for (int t = 0; t < ntiles; t++) {
        const int k0 = t * BK;

#pragma unroll
        for (int p = 0; p < 2; p++) {
            int krow = k0 + p * 32 + krr;
            f16x8 v = *(const f16x8*)(QKV + (size_t)krow * QLD + DIM_ + hkv * HD + kcc);
            const float* cr = fcos + krow * 64;
            const float* sr = fsin + krow * 64;
#pragma unroll
            for (int u = 0; u < 4; u++) {
                int fi = kcc / 2 + u;
                float cc = bf16r(cr[fi]), ss = bf16r(sr[fi]);
                float re = (float)v[2 * u], im = (float)v[2 * u + 1];
                v[2 * u]     = (f16_t)(re * cc - im * ss);
                v[2 * u + 1] = (f16_t)(re * ss + im * cc);
            }
            *(f16x8*)&Ks[p * 32 + krr][kcc] = v;
        }
#pragma unroll
        for (int p = 0; p < 2; p++)
            *(f16x8*)&Vs[p * 64 + vr][vc] =
                *(const f16x8*)(Vg + (size_t)(p * 64 + vr) * S_LEN + k0 + vc);
        __syncthreads();

        if (k0 <= q_hi) {
            floatx4 sc4[4] = {};
#pragma unroll
            for (int nt = 0; nt < 4; nt++)
#pragma unroll
                for (int ks = 0; ks < 4; ks++) {
                    f16x8 kf = *(const f16x8*)&Ks[nt * 16 + l16][ks * 32 + quad * 8];
                    sc4[nt] = __builtin_amdgcn_mfma_f32_16x16x32_f16(qf[ks], kf, sc4[nt], 0, 0, 0);
                }

            const bool needmask = (k0 + BK - 1) > q_lo;
#pragma unroll
            for (int nt = 0; nt < 4; nt++)
#pragma unroll
                for (int rg = 0; rg < 4; rg++) {
                    float s = sc4[nt][rg] * scale;
                    if (needmask) {
                        int qg = q_lo + quad * 4 + rg;
                        int kg = k0 + nt * 16 + l16;
                        if (kg > qg) s = -1e30f;
                    }
                    sc4[nt][rg] = s;
                }

            float alpha[4];
#pragma unroll
            for (int rg = 0; rg < 4; rg++) {
                float m = fmaxf(fmaxf(sc4[0][rg], sc4[1][rg]), fmaxf(sc4[2][rg], sc4[3][rg]));
#pragma unroll
                for (int off = 8; off >= 1; off >>= 1)
                    m = fmaxf(m, __shfl_xor(m, off, 64));
                float mn = fmaxf(m_run[rg], m);
                alpha[rg] = __expf(m_run[rg] - mn);
                m_run[rg] = mn;
            }
            float rsum[4] = {0.f, 0.f, 0.f, 0.f};
#pragma unroll
            for (int nt = 0; nt < 4; nt++)
#pragma unroll
                for (int rg = 0; rg < 4; rg++) {
                    float p = __expf(sc4[nt][rg] - m_run[rg]);
                    sc4[nt][rg] = p;
                    rsum[rg] += p;
                }
#pragma unroll
            for (int rg = 0; rg < 4; rg++) {
                float s = rsum[rg];
#pragma unroll
                for (int off = 8; off >= 1; off >>= 1)
                    s += __shfl_xor(s, off, 64);
                l_run[rg] = l_run[rg] * alpha[rg] + s;
            }
#pragma unroll
            for (int dt = 0; dt < 8; dt++)
#pragma unroll
                for (int rg = 0; rg < 4; rg++) o_acc[dt][rg] *= alpha[rg];

#pragma unroll
            for (int nt = 0; nt < 4; nt++)
#pragma unroll
                for (int rg = 0; rg < 4; rg++)
                    Ps[wave][quad * 4 + rg][nt * 16 + l16] = (f16_t)sc4[nt][rg];
            asm volatile("s_waitcnt lgkmcnt(0)" ::: "memory");
            __builtin_amdgcn_sched_barrier(0);

#pragma unroll
            for (int ks = 0; ks < 2; ks++) {
                f16x8 pf = *(const f16x8*)&Ps[wave][l16][ks * 32 + quad * 8];
#pragma unroll
                for (int dt = 0; dt < 8; dt++) {
                    f16x8 vf = *(const f16x8*)&Vs[dt * 16 + l16][ks * 32 + quad * 8];
                    o_acc[dt] = __builtin_amdgcn_mfma_f32_16x16x32_f16(pf, vf, o_acc[dt], 0, 0, 0);
                }
            }
        }
        __syncthreads();
    }

#pragma unroll
    for (int rg = 0; rg < 4; rg++) {
        float inv_l = 1.0f / l_run[rg];
#pragma unroll
        for (int dt = 0; dt < 8; dt++) {
            int row = q0 + wave * 16 + quad * 4 + rg;
            int col = h * HD + dt * 16 + l16;
            O[(size_t)row * (NH * HD) + col] = (f16_t)(o_acc[dt][rg] * inv_l);
        }
    }
}

// ---------------------------------------------------------------------------
// launch
// ---------------------------------------------------------------------------
extern "C" void kernel_launch(void* const* d_in, const int* in_sizes, int n_in,
                              void* d_out, int out_size, void* d_ws, size_t ws_size,
                              hipStream_t stream) {
    const float* x    = (const float*)d_in[0];
    const float* wq   = (const float*)d_in[1];
    const float* wk   = (const float*)d_in[2];
    const float* wv   = (const float*)d_in[3];
    const float* wo   = (const float*)d_in[4];
    const float* fcos = (const float*)d_in[5];
    const float* fsin = (const float*)d_in[6];
    float* out = (float*)d_out;

    char* ws = (char*)d_ws;
    constexpr size_t MB = 1024 * 1024;
    f16_t* xb    = (f16_t*)(ws + 0 * MB);     // 16 MB  [2048][4096]
    f16_t* wqkvT = (f16_t*)(ws + 16 * MB);    // 48 MB  [6144][4096]
    f16_t* woT   = (f16_t*)(ws + 64 * MB);    // 32 MB  [4096][4096]
    f16_t* QKVb  = (f16_t*)(ws + 96 * MB);    // 24 MB  [2048][6144]
    f16_t* Vt    = (f16_t*)(ws + 120 * MB);   //  4 MB  [8][128][2048]
    f16_t* attnb = (f16_t*)(ws + 124 * MB);   // 16 MB  [2048][4096]

    // 1. convert x; transpose-convert all weights (bf16 grid)
    f32_to_f16_kernel<<<S_LEN * DIM_ / 8 / 256, 256, 0, stream>>>(x, xb, S_LEN * DIM_);
    transpose_weights_kernel<<<40960, dim3(32, 8), 0, stream>>>(wq, wk, wv, wo, wqkvT, woT);

    // 2. fused QKV projection: [2048][4096] x [6144][4096]^T -> [2048][6144]
    //    256x256 tiles -> 24 x 8 = 192 blocks
    gemm_pipe_kernel<256, 256, f16_t><<<192, 512, 0, stream>>>(
        xb, wqkvT, QKVb, S_LEN, QLD, DIM_, QLD / 256);

    // 3. V^T: QKVb cols 5120..6143 -> Vt [8][128][2048]
    transpose_f16_kernel<<<dim3(KV_DIM / 32, S_LEN / 32), dim3(32, 8), 0, stream>>>(
        QKVb + 5120, Vt, QLD, S_LEN);

    // 4. causal flash attention (RoPE fused)
    attn_kernel<<<512, 512, 0, stream>>>(QKVb, Vt, fcos, fsin, attnb);

    // 5. output projection (fp32 out): 256x128 tiles -> 32 x 8 = 256 blocks
    gemm_pipe_kernel<256, 128, float><<<256, 512, 0, stream>>>(
        attnb, woT, out, S_LEN, DIM_, DIM_, DIM_ / 128);
}

// Round 4
// 522.053 us; speedup vs baseline: 1.1535x; 1.0763x over previous
//
#include <hip/hip_runtime.h>
#include <cstdint>
#include <cstddef>

typedef _Float16 f16_t;
typedef f16_t f16x8 __attribute__((ext_vector_type(8)));
typedef float  floatx4 __attribute__((ext_vector_type(4)));

#define S_LEN 2048
#define DIM_  4096
#define NH    32
#define NKV   8
#define HD    128
#define KV_DIM (NKV * HD)        // 1024
#define QLD   (DIM_ + 2 * KV_DIM) // 6144: fused QKV row stride

// round-to-nearest-even onto the bf16 grid, result stays fp32.
// (reference is computed from bf16-rounded inputs; we must share its grid.)
__device__ __forceinline__ float bf16r(float x) {
    uint32_t u = __float_as_uint(x);
    u = (u + 0x7fffu + ((u >> 16) & 1u)) & 0xffff0000u;
    return __uint_as_float(u);
}

// async global->LDS, 16B per lane (lane-contiguous LDS dest required)
__device__ __forceinline__ void gload_lds16(const f16_t* g, f16_t* l) {
    __builtin_amdgcn_global_load_lds(
        (const __attribute__((address_space(1))) void*)g,
        (__attribute__((address_space(3))) void*)l, 16, 0, 0);
}

// ---------------------------------------------------------------------------
// fp32 -> bf16-grid -> fp16 (lossless embed), 8 elements / thread
// ---------------------------------------------------------------------------
__global__ void f32_to_f16_kernel(const float* __restrict__ in,
                                  f16_t* __restrict__ out, int n) {
    int i = (blockIdx.x * blockDim.x + threadIdx.x) * 8;
    if (i >= n) return;
    float4 a = *(const float4*)(in + i);
    float4 b = *(const float4*)(in + i + 4);
    f16x8 o;
    o[0] = (f16_t)bf16r(a.x); o[1] = (f16_t)bf16r(a.y);
    o[2] = (f16_t)bf16r(a.z); o[3] = (f16_t)bf16r(a.w);
    o[4] = (f16_t)bf16r(b.x); o[5] = (f16_t)bf16r(b.y);
    o[6] = (f16_t)bf16r(b.z); o[7] = (f16_t)bf16r(b.w);
    *(f16x8*)(out + i) = o;
}

// ---------------------------------------------------------------------------
// all 4 weight transposes in ONE kernel (fp32 -> bf16 grid -> fp16).
// ---------------------------------------------------------------------------
__global__ void transpose_weights_kernel(const float* __restrict__ wq,
                                         const float* __restrict__ wk,
                                         const float* __restrict__ wv,
                                         const float* __restrict__ wo,
                                         f16_t* __restrict__ wqkvT,
                                         f16_t* __restrict__ woT) {
    __shared__ float tile[32][33];
    int bid = blockIdx.x;
    const float* in; f16_t* out; int C;
    if (bid < 16384)      { in = wq; out = wqkvT;                          C = 4096; }
    else if (bid < 20480) { bid -= 16384; in = wk; out = wqkvT + (size_t)4096 * 4096; C = 1024; }
    else if (bid < 24576) { bid -= 20480; in = wv; out = wqkvT + (size_t)5120 * 4096; C = 1024; }
    else                  { bid -= 24576; in = wo; out = woT;              C = 4096; }
    int gpr = C / 32;
    int bx = (bid % gpr) * 32;   // col offset in input
    int by = (bid / gpr) * 32;   // row offset in input (K dim, 4096)
    int tx = threadIdx.x, ty = threadIdx.y;
#pragma unroll
    for (int i = 0; i < 4; i++) {
        int r = ty + i * 8;
        tile[r][tx] = in[(size_t)(by + r) * C + bx + tx];
    }
    __syncthreads();
#pragma unroll
    for (int i = 0; i < 4; i++) {
        int r = ty + i * 8;
        out[(size_t)(bx + r) * 4096 + by + tx] = (f16_t)bf16r(tile[tx][r]);
    }
}

// ---------------------------------------------------------------------------
// generic fp16 transpose with strides: in [R][C] (ldi) -> out [C][R] (ldo)
// ---------------------------------------------------------------------------
__global__ void transpose_f16_kernel(const f16_t* __restrict__ in,
                                     f16_t* __restrict__ out,
                                     int ldi, int ldo) {
    __shared__ float tile[32][33];
    int bx = blockIdx.x * 32;  // C offset
    int by = blockIdx.y * 32;  // R offset
    int tx = threadIdx.x, ty = threadIdx.y;
#pragma unroll
    for (int i = 0; i < 4; i++) {
        int r = ty + i * 8;
        tile[r][tx] = (float)in[(size_t)(by + r) * ldi + bx + tx];
    }
    __syncthreads();
#pragma unroll
    for (int i = 0; i < 4; i++) {
        int r = ty + i * 8;
        out[(size_t)(bx + r) * ldo + by + tx] = (f16_t)tile[tx][r];
    }
}

// ---------------------------------------------------------------------------
// RoPE in-place over QKVb cols 0..5119 (Q and K), bf16-grid cos/sin, fp32
// math; Q additionally pre-scaled by 1/sqrt(HD). grid (5, 2048), block 128.
// ---------------------------------------------------------------------------
__global__ void rope_qk_kernel(f16_t* __restrict__ QKV,
                               const float* __restrict__ fcos,
                               const float* __restrict__ fsin) {
    int c8 = (blockIdx.x * blockDim.x + threadIdx.x) * 8;   // 0..5112
    int row = blockIdx.y;
    f16_t* p = QKV + (size_t)row * QLD + c8;
    f16x8 v = *(f16x8*)p;
    const float* cr = fcos + row * 64 + ((c8 & 127) >> 1);
    const float* sr = fsin + row * 64 + ((c8 & 127) >> 1);
    const float sc = (c8 < DIM_) ? 0.08838834764831845f : 1.0f;
#pragma unroll
    for (int u = 0; u < 4; u++) {
        float cc = bf16r(cr[u]), ss = bf16r(sr[u]);
        float re = (float)v[2 * u], im = (float)v[2 * u + 1];
        v[2 * u]     = (f16_t)((re * cc - im * ss) * sc);
        v[2 * u + 1] = (f16_t)((re * ss + im * cc) * sc);
    }
    *(f16x8*)p = v;
}

// ---------------------------------------------------------------------------
// Deep-pipelined fp16 GEMM: C[M][N] = A[M][K] @ BT[N][K]^T
// (unchanged from round 3: triple-buffer, counted vmcnt, T2 swizzle, XCD swz)
// ---------------------------------------------------------------------------
template <int BM, int BN, typename OutT>
__global__ __launch_bounds__(512) void gemm_pipe_kernel(
        const f16_t* __restrict__ A, const f16_t* __restrict__ BT,
        OutT* __restrict__ C, int M, int N, int K, int nbx) {
    constexpr int BK = 32;
    constexpr int WN = BN / 64;
    constexpr int WM = 8 / WN;
    constexpr int MT = BM / WM / 16;
    constexpr int NT = 4;
    constexpr int ABY = BM * BK * 2;
    constexpr int BBY = BN * BK * 2;
    constexpr int AISS = ABY / 8192;
    constexpr int BISS = BBY / 8192;
    constexpr int LOADS = AISS + BISS;
    constexpr int BUF_EL = (ABY + BBY) / 2;

    __shared__ f16_t lds[3 * BUF_EL];

    const int tid  = threadIdx.x;
    const int lane = tid & 63;
    const int wave = tid >> 6;
    const int quad = lane >> 4;
    const int l16  = lane & 15;
    const int wn = (wave % WN) * 64;
    const int wm = (wave / WN) * (BM / WM);

    const int nwg = gridDim.x;
    const int swz = (blockIdx.x & 7) * (nwg >> 3) + (blockIdx.x >> 3);
    const int m0 = (swz / nbx) * BM;
    const int n0 = (swz % nbx) * BN;

    const f16_t* Arow = A  + (size_t)m0 * K;
    const f16_t* Brow = BT + (size_t)n0 * K;
    const int nt_tiles = K / BK;

    floatx4 acc[MT][NT] = {};

    auto stage = [&](int t, int q) {
        const int k0 = t * BK;
        f16_t* LdA = lds + q * BUF_EL;
#pragma unroll
        for (int j = 0; j < AISS; j++) {
            int Lb  = j * 8192 + tid * 16;
            int row = Lb >> 6;
            int cb  = (Lb & 48) ^ (((Lb >> 7) & 3) << 4);
            gload_lds16(Arow + (size_t)row * K + k0 + (cb >> 1), LdA + (Lb >> 1));
        }
        f16_t* LdB = lds + q * BUF_EL + ABY / 2;
#pragma unroll
        for (int j = 0; j < BISS; j++) {
            int Lb  = j * 8192 + tid * 16;
            int row = Lb >> 6;
            int cb  = (Lb & 48) ^ (((Lb >> 7) & 3) << 4);
            gload_lds16(Brow + (size_t)row * K + k0 + (cb >> 1), LdB + (Lb >> 1));
        }
    };

    stage(0, 0);
    stage(1, 1);
    if constexpr (LOADS == 4) asm volatile("s_waitcnt vmcnt(4)" ::: "memory");
    else                      asm volatile("s_waitcnt vmcnt(3)" ::: "memory");
    __builtin_amdgcn_s_barrier();
    __builtin_amdgcn_sched_barrier(0);

    for (int t = 0; t < nt_tiles; ++t) {
        const int cur = t % 3;
        const bool pre = (t + 2 < nt_tiles);
        if (pre) stage(t + 2, (t + 2) % 3);

        const f16_t* Ab = lds + cur * BUF_EL;
        const f16_t* Bb = Ab + ABY / 2;
        f16x8 af[MT], bf[NT];
#pragma unroll
        for (int mt = 0; mt < MT; mt++) {
            int r  = wm + mt * 16 + l16;
            int cb = (quad * 16) ^ (((r >> 1) & 3) << 4);
            af[mt] = *(const f16x8*)(Ab + r * 32 + (cb >> 1));
        }
#pragma unroll
        for (int nt = 0; nt < NT; nt++) {
            int r  = wn + nt * 16 + l16;
            int cb = (quad * 16) ^ (((r >> 1) & 3) << 4);
            bf[nt] = *(const f16x8*)(Bb + r * 32 + (cb >> 1));
        }
        asm volatile("s_waitcnt lgkmcnt(0)" ::: "memory");
        __builtin_amdgcn_sched_barrier(0);
        __builtin_amdgcn_s_setprio(1);
#pragma unroll
        for (int mt = 0; mt < MT; mt++)
#pragma unroll
            for (int nt = 0; nt < NT; nt++)
                acc[mt][nt] = __builtin_amdgcn_mfma_f32_16x16x32_f16(
                    af[mt], bf[nt], acc[mt][nt], 0, 0, 0);
        __builtin_amdgcn_s_setprio(0);
        if (pre) {
            if constexpr (LOADS == 4) asm volatile("s_waitcnt vmcnt(4)" ::: "memory");
            else                      asm volatile("s_waitcnt vmcnt(3)" ::: "memory");
        } else {
            asm volatile("s_waitcnt vmcnt(0)" ::: "memory");
        }
        __builtin_amdgcn_s_barrier();
        __builtin_amdgcn_sched_barrier(0);
    }

#pragma unroll
    for (int mt = 0; mt < MT; mt++)
#pragma unroll
        for (int nt = 0; nt < NT; nt++)
#pragma unroll
            for (int rg = 0; rg < 4; rg++) {
                int row = m0 + wm + mt * 16 + quad * 4 + rg;
                int col = n0 + wn + nt * 16 + l16;
                C[(size_t)row * N + col] = (OutT)acc[mt][nt][rg];
            }
}

// ---------------------------------------------------------------------------
// Flash attention, causal. Q/K pre-roped (Q pre-scaled by 1/sqrt(HD)).
//  QKV [S][6144] fp16, Vt [NKV][HD][S] fp16, O [S][4096] fp16
// 512 thr = 8 waves; BQ=128 (16 rows/wave); K-tiles of 64.
// K/V staged via global_load_lds with inverse-XOR-swizzled per-lane global
// source (linear LDS dest), XOR applied again on ds_read -> conflict-free.
// l via ones-column MFMA; defer-max (THR=8) skips rescale on stable tiles.
// ---------------------------------------------------------------------------
__global__ __launch_bounds__(512) void attn_kernel(
        const f16_t* __restrict__ QKV, const f16_t* __restrict__ Vt,
        f16_t* __restrict__ O) {
    constexpr int BK = 64;
    __shared__ f16_t Ks[BK * HD];    // 16 KB, 256B rows, XOR-swizzled
    __shared__ f16_t Vs[HD * BK];    // 16 KB, 128B rows, XOR-swizzled
    __shared__ f16_t Ps[8][16][72];  // 18 KB (wave-private rows)

    const int tid  = threadIdx.x;
    const int lane = tid & 63;
    const int wave = tid >> 6;
    const int quad = lane >> 4;
    const int l16  = lane & 15;

    const int bid = blockIdx.x;
    const int h   = bid & 31;
    const int g   = bid >> 5;
    const int qt  = (g < 8) ? g : 23 - g;
    const int q0  = qt * 128;
    const int hkv = h >> 2;

    // ---- Q fragments (pre-roped, pre-scaled: pure copy) ----
    const int qrow = q0 + wave * 16 + l16;
    const f16_t* Qg = QKV + (size_t)qrow * QLD + h * HD;
    f16x8 qf[4];
#pragma unroll
    for (int c = 0; c < 4; c++) qf[c] = *(const f16x8*)(Qg + c * 32 + quad * 8);

    floatx4 o_acc[8] = {};
    floatx4 l_acc = {0.f, 0.f, 0.f, 0.f};
    float m_run[4];
#pragma unroll
    for (int i = 0; i < 4; i++) m_run[i] = -1e30f;

    f16x8 ones;
#pragma unroll
    for (int i = 0; i < 8; i++) ones[i] = (f16_t)1.0f;

    const int q_lo = q0 + wave * 16;
    const int q_hi = q_lo + 15;
    const int ntiles = q0 / BK + 2;

    // ---- staging pointers (inverse-swizzled global source) ----
    // Ks: LDS byte L=j*8192+tid*16 -> row r=L>>8, off=L&255; src col = (off^((r&7)<<4))>>1
    const int rK = tid >> 4;                       // 0..31 ; j=1 adds 32 (same r&7)
    const int cK = (((tid & 15) * 16) ^ ((rK & 7) << 4)) >> 1;
    const f16_t* pK = QKV + (size_t)rK * QLD + DIM_ + hkv * HD + cK;
    // Vs: L -> r=L>>7 (0..63; j=1 adds 64), off=L&127
    const int rV = tid >> 3;
    const int cV = (((tid & 7) * 16) ^ ((rV & 7) << 4)) >> 1;
    const f16_t* pV = Vt + (size_t)hkv * HD * S_LEN + (size_t)rV * S_LEN + cV;
    f16_t* KsD0 = Ks + tid * 8;  f16_t* KsD1 = KsD0 + 4096;
    f16_t* VsD0 = Vs + tid * 8;  f16_t* VsD1 = VsD0 + 4096;

    for (int t = 0; t < ntiles; t++) {
        const int k0 = t * BK;

        // ---- stage K + V^T tiles (pure DMA) ----
        gload_lds16(pK + (size_t)k0 * QLD, KsD0);
        gload_lds16(pK + (size_t)(k0 + 32) * QLD, KsD1);
        gload_lds16(pV + k0, VsD0);
        gload_lds16(pV + k0 + (size_t)64 * S_LEN, VsD1);
        asm volatile("s_waitcnt vmcnt(0)" ::: "memory");
        __syncthreads();

        if (k0 <= q_hi) {
            // ---- S = Q K^T (16 x 64), already includes 1/sqrt(d) via Q ----
            floatx4 sc4[4] = {};
#pragma unroll
            for (int nt = 0; nt < 4; nt++) {
                const int r = nt * 16 + l16;
#pragma unroll
                for (int ks = 0; ks < 4; ks++) {
                    int cb = (ks * 64 + quad * 16) ^ ((r & 7) << 4);
                    f16x8 kf = *(const f16x8*)(Ks + r * 128 + (cb >> 1));
                    sc4[nt] = __builtin_amdgcn_mfma_f32_16x16x32_f16(qf[ks], kf, sc4[nt], 0, 0, 0);
                }
            }

            if ((k0 + BK - 1) > q_lo) {  // diagonal tile: apply causal mask
#pragma unroll
                for (int nt = 0; nt < 4; nt++)
#pragma unroll
                    for (int rg = 0; rg < 4; rg++) {
                        int qg = q_lo + quad * 4 + rg;
                        int kg = k0 + nt * 16 + l16;
                        if (kg > qg) sc4[nt][rg] = -1e30f;
                    }
            }

            // ---- tile max + defer-max (THR=8) ----
            float m_t[4];
#pragma unroll
            for (int rg = 0; rg < 4; rg++) {
                float m = fmaxf(fmaxf(sc4[0][rg], sc4[1][rg]), fmaxf(sc4[2][rg], sc4[3][rg]));
#pragma unroll
                for (int off = 8; off >= 1; off >>= 1)
                    m = fmaxf(m, __shfl_xor(m, off, 64));
                m_t[rg] = m;
            }
            int grow = (m_t[0] > m_run[0] + 8.f) | (m_t[1] > m_run[1] + 8.f) |
                       (m_t[2] > m_run[2] + 8.f) | (m_t[3] > m_run[3] + 8.f);
            if (__any(grow)) {
                float alpha[4];
#pragma unroll
                for (int rg = 0; rg < 4; rg++) {
                    float mn = fmaxf(m_run[rg], m_t[rg]);
                    alpha[rg] = __expf(m_run[rg] - mn);
                    m_run[rg] = mn;
                }
#pragma unroll
                for (int dt = 0; dt < 8; dt++)
#pragma unroll
                    for (int rg = 0; rg < 4; rg++) o_acc[dt][rg] *= alpha[rg];
#pragma unroll
                for (int rg = 0; rg < 4; rg++) l_acc[rg] *= alpha[rg];
            }

            // ---- P = exp(S - m), write to wave-private LDS ----
#pragma unroll
            for (int nt = 0; nt < 4; nt++)
#pragma unroll
                for (int rg = 0; rg < 4; rg++)
                    Ps[wave][quad * 4 + rg][nt * 16 + l16] =
                        (f16_t)__expf(sc4[nt][rg] - m_run[rg]);
            asm volatile("s_waitcnt lgkmcnt(0)" ::: "memory");
            __builtin_amdgcn_sched_barrier(0);

            // ---- O += P V ; l += P @ ones ----
#pragma unroll
            for (int ks = 0; ks < 2; ks++) {
                f16x8 pf = *(const f16x8*)&Ps[wave][l16][ks * 32 + quad * 8];
                l_acc = __builtin_amdgcn_mfma_f32_16x16x32_f16(pf, ones, l_acc, 0, 0, 0);
#pragma unroll
                for (int dt = 0; dt < 8; dt++) {
                    const int r = dt * 16 + l16;
                    int cb = (ks * 64 + quad * 16) ^ ((r & 7) << 4);
                    f16x8 vf = *(const f16x8*)(Vs + r * 64 + (cb >> 1));
                    o_acc[dt] = __builtin_amdgcn_mfma_f32_16x16x32_f16(pf, vf, o_acc[dt], 0, 0, 0);
                }
            }
        }
        __syncthreads();
    }

    // ---- epilogue ----
#pragma unroll
    for (int rg = 0; rg < 4; rg++) {
        float inv_l = 1.0f / l_acc[rg];
#pragma unroll
        for (int dt = 0; dt < 8; dt++) {
            int row = q0 + wave * 16 + quad * 4 + rg;
            int col = h * HD + dt * 16 + l16;
            O[(size_t)row * (NH * HD) + col] = (f16_t)(o_acc[dt][rg] * inv_l);
        }
    }
}

// ---------------------------------------------------------------------------
// launch
// ---------------------------------------------------------------------------
extern "C" void kernel_launch(void* const* d_in, const int* in_sizes, int n_in,
                              void* d_out, int out_size, void* d_ws, size_t ws_size,
                              hipStream_t stream) {
    const float* x    = (const float*)d_in[0];
    const float* wq   = (const float*)d_in[1];
    const float* wk   = (const float*)d_in[2];
    const float* wv   = (const float*)d_in[3];
    const float* wo   = (const float*)d_in[4];
    const float* fcos = (const float*)d_in[5];
    const float* fsin = (const float*)d_in[6];
    float* out = (float*)d_out;

    char* ws = (char*)d_ws;
    constexpr size_t MB = 1024 * 1024;
    f16_t* xb    = (f16_t*)(ws + 0 * MB);     // 16 MB  [2048][4096]
    f16_t* wqkvT = (f16_t*)(ws + 16 * MB);    // 48 MB  [6144][4096]
    f16_t* woT   = (f16_t*)(ws + 64 * MB);    // 32 MB  [4096][4096]
    f16_t* QKVb  = (f16_t*)(ws + 96 * MB);    // 24 MB  [2048][6144]
    f16_t* Vt    = (f16_t*)(ws + 120 * MB);   //  4 MB  [8][128][2048]
    f16_t* attnb = (f16_t*)(ws + 124 * MB);   // 16 MB  [2048][4096]

    // 1. convert x; transpose-convert all weights (bf16 grid)
    f32_to_f16_kernel<<<S_LEN * DIM_ / 8 / 256, 256, 0, stream>>>(x, xb, S_LEN * DIM_);
    transpose_weights_kernel<<<40960, dim3(32, 8), 0, stream>>>(wq, wk, wv, wo, wqkvT, woT);

    // 2. fused QKV projection: [2048][4096] x [6144][4096]^T -> [2048][6144]
    gemm_pipe_kernel<256, 256, f16_t><<<192, 512, 0, stream>>>(
        xb, wqkvT, QKVb, S_LEN, QLD, DIM_, QLD / 256);

    // 3. RoPE Q+K in-place (Q pre-scaled); V^T transpose
    rope_qk_kernel<<<dim3(5, S_LEN), 128, 0, stream>>>(QKVb, fcos, fsin);
    transpose_f16_kernel<<<dim3(KV_DIM / 32, S_LEN / 32), dim3(32, 8), 0, stream>>>(
        QKVb + 5120, Vt, QLD, S_LEN);

    // 4. causal flash attention
    attn_kernel<<<512, 512, 0, stream>>>(QKVb, Vt, attnb);

    // 5. output projection (fp32 out): 256x128 tiles -> 256 blocks
    gemm_pipe_kernel<256, 128, float><<<256, 512, 0, stream>>>(
        attnb, woT, out, S_LEN, DIM_, DIM_, DIM_ / 128);
}

// Round 5
// 507.149 us; speedup vs baseline: 1.1874x; 1.0294x over previous
//
#include <hip/hip_runtime.h>
#include <cstdint>
#include <cstddef>

typedef _Float16 f16_t;
typedef f16_t f16x8 __attribute__((ext_vector_type(8)));
typedef float  floatx4 __attribute__((ext_vector_type(4)));

#define S_LEN 2048
#define DIM_  4096
#define NH    32
#define NKV   8
#define HD    128
#define KV_DIM (NKV * HD)        // 1024
#define QLD   (DIM_ + 2 * KV_DIM) // 6144: fused QKV row stride

// round-to-nearest-even onto the bf16 grid, result stays fp32.
// (reference is computed from bf16-rounded inputs; we must share its grid.)
__device__ __forceinline__ float bf16r(float x) {
    uint32_t u = __float_as_uint(x);
    u = (u + 0x7fffu + ((u >> 16) & 1u)) & 0xffff0000u;
    return __uint_as_float(u);
}

// async global->LDS, 16B per lane (lane-contiguous LDS dest required)
__device__ __forceinline__ void gload_lds16(const f16_t* g, f16_t* l) {
    __builtin_amdgcn_global_load_lds(
        (const __attribute__((address_space(1))) void*)g,
        (__attribute__((address_space(3))) void*)l, 16, 0, 0);
}

// ---------------------------------------------------------------------------
// fp32 -> bf16-grid -> fp16 (lossless embed), 8 elements / thread
// ---------------------------------------------------------------------------
__global__ void f32_to_f16_kernel(const float* __restrict__ in,
                                  f16_t* __restrict__ out, int n) {
    int i = (blockIdx.x * blockDim.x + threadIdx.x) * 8;
    if (i >= n) return;
    float4 a = *(const float4*)(in + i);
    float4 b = *(const float4*)(in + i + 4);
    f16x8 o;
    o[0] = (f16_t)bf16r(a.x); o[1] = (f16_t)bf16r(a.y);
    o[2] = (f16_t)bf16r(a.z); o[3] = (f16_t)bf16r(a.w);
    o[4] = (f16_t)bf16r(b.x); o[5] = (f16_t)bf16r(b.y);
    o[6] = (f16_t)bf16r(b.z); o[7] = (f16_t)bf16r(b.w);
    *(f16x8*)(out + i) = o;
}

// ---------------------------------------------------------------------------
// all 4 weight transposes in ONE kernel (fp32 -> bf16 grid -> fp16).
// ---------------------------------------------------------------------------
__global__ void transpose_weights_kernel(const float* __restrict__ wq,
                                         const float* __restrict__ wk,
                                         const float* __restrict__ wv,
                                         const float* __restrict__ wo,
                                         f16_t* __restrict__ wqkvT,
                                         f16_t* __restrict__ woT) {
    __shared__ float tile[32][33];
    int bid = blockIdx.x;
    const float* in; f16_t* out; int C;
    if (bid < 16384)      { in = wq; out = wqkvT;                          C = 4096; }
    else if (bid < 20480) { bid -= 16384; in = wk; out = wqkvT + (size_t)4096 * 4096; C = 1024; }
    else if (bid < 24576) { bid -= 20480; in = wv; out = wqkvT + (size_t)5120 * 4096; C = 1024; }
    else                  { bid -= 24576; in = wo; out = woT;              C = 4096; }
    int gpr = C / 32;
    int bx = (bid % gpr) * 32;   // col offset in input
    int by = (bid / gpr) * 32;   // row offset in input (K dim, 4096)
    int tx = threadIdx.x, ty = threadIdx.y;
#pragma unroll
    for (int i = 0; i < 4; i++) {
        int r = ty + i * 8;
        tile[r][tx] = in[(size_t)(by + r) * C + bx + tx];
    }
    __syncthreads();
#pragma unroll
    for (int i = 0; i < 4; i++) {
        int r = ty + i * 8;
        out[(size_t)(bx + r) * 4096 + by + tx] = (f16_t)bf16r(tile[tx][r]);
    }
}

// ---------------------------------------------------------------------------
// generic fp16 transpose with strides: in [R][C] (ldi) -> out [C][R] (ldo)
// ---------------------------------------------------------------------------
__global__ void transpose_f16_kernel(const f16_t* __restrict__ in,
                                     f16_t* __restrict__ out,
                                     int ldi, int ldo) {
    __shared__ float tile[32][33];
    int bx = blockIdx.x * 32;  // C offset
    int by = blockIdx.y * 32;  // R offset
    int tx = threadIdx.x, ty = threadIdx.y;
#pragma unroll
    for (int i = 0; i < 4; i++) {
        int r = ty + i * 8;
        tile[r][tx] = (float)in[(size_t)(by + r) * ldi + bx + tx];
    }
    __syncthreads();
#pragma unroll
    for (int i = 0; i < 4; i++) {
        int r = ty + i * 8;
        out[(size_t)(bx + r) * ldo + by + tx] = (f16_t)tile[tx][r];
    }
}

// ---------------------------------------------------------------------------
// RoPE in-place over QKVb cols 0..5119 (Q and K), bf16-grid cos/sin, fp32
// math; Q additionally pre-scaled by 1/sqrt(HD). grid (5, 2048), block 128.
// ---------------------------------------------------------------------------
__global__ void rope_qk_kernel(f16_t* __restrict__ QKV,
                               const float* __restrict__ fcos,
                               const float* __restrict__ fsin) {
    int c8 = (blockIdx.x * blockDim.x + threadIdx.x) * 8;   // 0..5112
    int row = blockIdx.y;
    f16_t* p = QKV + (size_t)row * QLD + c8;
    f16x8 v = *(f16x8*)p;
    const float* cr = fcos + row * 64 + ((c8 & 127) >> 1);
    const float* sr = fsin + row * 64 + ((c8 & 127) >> 1);
    const float sc = (c8 < DIM_) ? 0.08838834764831845f : 1.0f;
#pragma unroll
    for (int u = 0; u < 4; u++) {
        float cc = bf16r(cr[u]), ss = bf16r(sr[u]);
        float re = (float)v[2 * u], im = (float)v[2 * u + 1];
        v[2 * u]     = (f16_t)((re * cc - im * ss) * sc);
        v[2 * u + 1] = (f16_t)((re * ss + im * cc) * sc);
    }
    *(f16x8*)p = v;
}

// ---------------------------------------------------------------------------
// Deep-pipelined fp16 GEMM: C[M][N] = A[M][K] @ BT[N][K]^T
// Triple-buffered LDS, prefetch distance 2, counted vmcnt (never 0 in
// steady state), T2 XOR-swizzle, XCD-chunked block swizzle.
// R4 change: NO forced lgkmcnt(0) drain between ds_reads and MFMAs —
// the compiler's dependency-driven fine-grained lgkmcnt interleaves
// ds_read with MFMA (m97/m141 evidence: forced order-pinning is a ~40%
// pessimization). Safety: all ds_read results are register-consumed by
// MFMAs before the end-of-iter barrier; buffer overwrite is 2 barriers
// later in a different buffer.
// ---------------------------------------------------------------------------
template <int BM, int BN, typename OutT>
__global__ __launch_bounds__(512) void gemm_pipe_kernel(
        const f16_t* __restrict__ A, const f16_t* __restrict__ BT,
        OutT* __restrict__ C, int M, int N, int K, int nbx) {
    constexpr int BK = 32;
    constexpr int WN = BN / 64;
    constexpr int WM = 8 / WN;
    constexpr int MT = BM / WM / 16;
    constexpr int NT = 4;
    constexpr int ABY = BM * BK * 2;
    constexpr int BBY = BN * BK * 2;
    constexpr int AISS = ABY / 8192;
    constexpr int BISS = BBY / 8192;
    constexpr int LOADS = AISS + BISS;
    constexpr int BUF_EL = (ABY + BBY) / 2;

    __shared__ f16_t lds[3 * BUF_EL];

    const int tid  = threadIdx.x;
    const int lane = tid & 63;
    const int wave = tid >> 6;
    const int quad = lane >> 4;
    const int l16  = lane & 15;
    const int wn = (wave % WN) * 64;
    const int wm = (wave / WN) * (BM / WM);

    const int nwg = gridDim.x;
    const int swz = (blockIdx.x & 7) * (nwg >> 3) + (blockIdx.x >> 3);
    const int m0 = (swz / nbx) * BM;
    const int n0 = (swz % nbx) * BN;

    const f16_t* Arow = A  + (size_t)m0 * K;
    const f16_t* Brow = BT + (size_t)n0 * K;
    const int nt_tiles = K / BK;

    floatx4 acc[MT][NT] = {};

    auto stage = [&](int t, int q) {
        const int k0 = t * BK;
        f16_t* LdA = lds + q * BUF_EL;
#pragma unroll
        for (int j = 0; j < AISS; j++) {
            int Lb  = j * 8192 + tid * 16;
            int row = Lb >> 6;
            int cb  = (Lb & 48) ^ (((Lb >> 7) & 3) << 4);
            gload_lds16(Arow + (size_t)row * K + k0 + (cb >> 1), LdA + (Lb >> 1));
        }
        f16_t* LdB = lds + q * BUF_EL + ABY / 2;
#pragma unroll
        for (int j = 0; j < BISS; j++) {
            int Lb  = j * 8192 + tid * 16;
            int row = Lb >> 6;
            int cb  = (Lb & 48) ^ (((Lb >> 7) & 3) << 4);
            gload_lds16(Brow + (size_t)row * K + k0 + (cb >> 1), LdB + (Lb >> 1));
        }
    };

    stage(0, 0);
    stage(1, 1);
    if constexpr (LOADS == 4) asm volatile("s_waitcnt vmcnt(4)" ::: "memory");
    else                      asm volatile("s_waitcnt vmcnt(3)" ::: "memory");
    __builtin_amdgcn_s_barrier();
    __builtin_amdgcn_sched_barrier(0);

    for (int t = 0; t < nt_tiles; ++t) {
        const int cur = t % 3;
        const bool pre = (t + 2 < nt_tiles);
        if (pre) stage(t + 2, (t + 2) % 3);

        const f16_t* Ab = lds + cur * BUF_EL;
        const f16_t* Bb = Ab + ABY / 2;
        f16x8 af[MT], bf[NT];
#pragma unroll
        for (int mt = 0; mt < MT; mt++) {
            int r  = wm + mt * 16 + l16;
            int cb = (quad * 16) ^ (((r >> 1) & 3) << 4);
            af[mt] = *(const f16x8*)(Ab + r * 32 + (cb >> 1));
        }
#pragma unroll
        for (int nt = 0; nt < NT; nt++) {
            int r  = wn + nt * 16 + l16;
            int cb = (quad * 16) ^ (((r >> 1) & 3) << 4);
            bf[nt] = *(const f16x8*)(Bb + r * 32 + (cb >> 1));
        }
        // no forced lgkmcnt(0): compiler interleaves ds_read waits with MFMAs
        __builtin_amdgcn_s_setprio(1);
#pragma unroll
        for (int mt = 0; mt < MT; mt++)
#pragma unroll
            for (int nt = 0; nt < NT; nt++)
                acc[mt][nt] = __builtin_amdgcn_mfma_f32_16x16x32_f16(
                    af[mt], bf[nt], acc[mt][nt], 0, 0, 0);
        __builtin_amdgcn_s_setprio(0);
        if (pre) {
            if constexpr (LOADS == 4) asm volatile("s_waitcnt vmcnt(4)" ::: "memory");
            else                      asm volatile("s_waitcnt vmcnt(3)" ::: "memory");
        } else {
            asm volatile("s_waitcnt vmcnt(0)" ::: "memory");
        }
        __builtin_amdgcn_s_barrier();
        __builtin_amdgcn_sched_barrier(0);
    }

#pragma unroll
    for (int mt = 0; mt < MT; mt++)
#pragma unroll
        for (int nt = 0; nt < NT; nt++)
#pragma unroll
            for (int rg = 0; rg < 4; rg++) {
                int row = m0 + wm + mt * 16 + quad * 4 + rg;
                int col = n0 + wn + nt * 16 + l16;
                C[(size_t)row * N + col] = (OutT)acc[mt][nt][rg];
            }
}

// ---------------------------------------------------------------------------
// Flash attention, causal. Q/K pre-roped (Q pre-scaled by 1/sqrt(HD)).
// (unchanged from round 4)
// ---------------------------------------------------------------------------
__global__ __launch_bounds__(512) void attn_kernel(
        const f16_t* __restrict__ QKV, const f16_t* __restrict__ Vt,
        f16_t* __restrict__ O) {
    constexpr int BK = 64;
    __shared__ f16_t Ks[BK * HD];    // 16 KB, 256B rows, XOR-swizzled
    __shared__ f16_t Vs[HD * BK];    // 16 KB, 128B rows, XOR-swizzled
    __shared__ f16_t Ps[8][16][72];  // 18 KB (wave-private rows)

    const int tid  = threadIdx.x;
    const int lane = tid & 63;
    const int wave = tid >> 6;
    const int quad = lane >> 4;
    const int l16  = lane & 15;

    const int bid = blockIdx.x;
    const int h   = bid & 31;
    const int g   = bid >> 5;
    const int qt  = (g < 8) ? g : 23 - g;
    const int q0  = qt * 128;
    const int hkv = h >> 2;

    const int qrow = q0 + wave * 16 + l16;
    const f16_t* Qg = QKV + (size_t)qrow * QLD + h * HD;
    f16x8 qf[4];
#pragma unroll
    for (int c = 0; c < 4; c++) qf[c] = *(const f16x8*)(Qg + c * 32 + quad * 8);

    floatx4 o_acc[8] = {};
    floatx4 l_acc = {0.f, 0.f, 0.f, 0.f};
    float m_run[4];
#pragma unroll
    for (int i = 0; i < 4; i++) m_run[i] = -1e30f;

    f16x8 ones;
#pragma unroll
    for (int i = 0; i < 8; i++) ones[i] = (f16_t)1.0f;

    const int q_lo = q0 + wave * 16;
    const int q_hi = q_lo + 15;
    const int ntiles = q0 / BK + 2;

    const int rK = tid >> 4;
    const int cK = (((tid & 15) * 16) ^ ((rK & 7) << 4)) >> 1;
    const f16_t* pK = QKV + (size_t)rK * QLD + DIM_ + hkv * HD + cK;
    const int rV = tid >> 3;
    const int cV = (((tid & 7) * 16) ^ ((rV & 7) << 4)) >> 1;
    const f16_t* pV = Vt + (size_t)hkv * HD * S_LEN + (size_t)rV * S_LEN + cV;
    f16_t* KsD0 = Ks + tid * 8;  f16_t* KsD1 = KsD0 + 4096;
    f16_t* VsD0 = Vs + tid * 8;  f16_t* VsD1 = VsD0 + 4096;

    for (int t = 0; t < ntiles; t++) {
        const int k0 = t * BK;

        gload_lds16(pK + (size_t)k0 * QLD, KsD0);
        gload_lds16(pK + (size_t)(k0 + 32) * QLD, KsD1);
        gload_lds16(pV + k0, VsD0);
        gload_lds16(pV + k0 + (size_t)64 * S_LEN, VsD1);
        asm volatile("s_waitcnt vmcnt(0)" ::: "memory");
        __syncthreads();

        if (k0 <= q_hi) {
            floatx4 sc4[4] = {};
#pragma unroll
            for (int nt = 0; nt < 4; nt++) {
                const int r = nt * 16 + l16;
#pragma unroll
                for (int ks = 0; ks < 4; ks++) {
                    int cb = (ks * 64 + quad * 16) ^ ((r & 7) << 4);
                    f16x8 kf = *(const f16x8*)(Ks + r * 128 + (cb >> 1));
                    sc4[nt] = __builtin_amdgcn_mfma_f32_16x16x32_f16(qf[ks], kf, sc4[nt], 0, 0, 0);
                }
            }

            if ((k0 + BK - 1) > q_lo) {
#pragma unroll
                for (int nt = 0; nt < 4; nt++)
#pragma unroll
                    for (int rg = 0; rg < 4; rg++) {
                        int qg = q_lo + quad * 4 + rg;
                        int kg = k0 + nt * 16 + l16;
                        if (kg > qg) sc4[nt][rg] = -1e30f;
                    }
            }

            float m_t[4];
#pragma unroll
            for (int rg = 0; rg < 4; rg++) {
                float m = fmaxf(fmaxf(sc4[0][rg], sc4[1][rg]), fmaxf(sc4[2][rg], sc4[3][rg]));
#pragma unroll
                for (int off = 8; off >= 1; off >>= 1)
                    m = fmaxf(m, __shfl_xor(m, off, 64));
                m_t[rg] = m;
            }
            int grow = (m_t[0] > m_run[0] + 8.f) | (m_t[1] > m_run[1] + 8.f) |
                       (m_t[2] > m_run[2] + 8.f) | (m_t[3] > m_run[3] + 8.f);
            if (__any(grow)) {
                float alpha[4];
#pragma unroll
                for (int rg = 0; rg < 4; rg++) {
                    float mn = fmaxf(m_run[rg], m_t[rg]);
                    alpha[rg] = __expf(m_run[rg] - mn);
                    m_run[rg] = mn;
                }
#pragma unroll
                for (int dt = 0; dt < 8; dt++)
#pragma unroll
                    for (int rg = 0; rg < 4; rg++) o_acc[dt][rg] *= alpha[rg];
#pragma unroll
                for (int rg = 0; rg < 4; rg++) l_acc[rg] *= alpha[rg];
            }

#pragma unroll
            for (int nt = 0; nt < 4; nt++)
#pragma unroll
                for (int rg = 0; rg < 4; rg++)
                    Ps[wave][quad * 4 + rg][nt * 16 + l16] =
                        (f16_t)__expf(sc4[nt][rg] - m_run[rg]);
            asm volatile("s_waitcnt lgkmcnt(0)" ::: "memory");
            __builtin_amdgcn_sched_barrier(0);

#pragma unroll
            for (int ks = 0; ks < 2; ks++) {
                f16x8 pf = *(const f16x8*)&Ps[wave][l16][ks * 32 + quad * 8];
                l_acc = __builtin_amdgcn_mfma_f32_16x16x32_f16(pf, ones, l_acc, 0, 0, 0);
#pragma unroll
                for (int dt = 0; dt < 8; dt++) {
                    const int r = dt * 16 + l16;
                    int cb = (ks * 64 + quad * 16) ^ ((r & 7) << 4);
                    f16x8 vf = *(const f16x8*)(Vs + r * 64 + (cb >> 1));
                    o_acc[dt] = __builtin_amdgcn_mfma_f32_16x16x32_f16(pf, vf, o_acc[dt], 0, 0, 0);
                }
            }
        }
        __syncthreads();
    }

#pragma unroll
    for (int rg = 0; rg < 4; rg++) {
        float inv_l = 1.0f / l_acc[rg];
#pragma unroll
        for (int dt = 0; dt < 8; dt++) {
            int row = q0 + wave * 16 + quad * 4 + rg;
            int col = h * HD + dt * 16 + l16;
            O[(size_t)row * (NH * HD) + col] = (f16_t)(o_acc[dt][rg] * inv_l);
        }
    }
}

// ---------------------------------------------------------------------------
// launch
// ---------------------------------------------------------------------------
extern "C" void kernel_launch(void* const* d_in, const int* in_sizes, int n_in,
                              void* d_out, int out_size, void* d_ws, size_t ws_size,
                              hipStream_t stream) {
    const float* x    = (const float*)d_in[0];
    const float* wq   = (const float*)d_in[1];
    const float* wk   = (const float*)d_in[2];
    const float* wv   = (const float*)d_in[3];
    const float* wo   = (const float*)d_in[4];
    const float* fcos = (const float*)d_in[5];
    const float* fsin = (const float*)d_in[6];
    float* out = (float*)d_out;

    char* ws = (char*)d_ws;
    constexpr size_t MB = 1024 * 1024;
    f16_t* xb    = (f16_t*)(ws + 0 * MB);     // 16 MB  [2048][4096]
    f16_t* wqkvT = (f16_t*)(ws + 16 * MB);    // 48 MB  [6144][4096]
    f16_t* woT   = (f16_t*)(ws + 64 * MB);    // 32 MB  [4096][4096]
    f16_t* QKVb  = (f16_t*)(ws + 96 * MB);    // 24 MB  [2048][6144]
    f16_t* Vt    = (f16_t*)(ws + 120 * MB);   //  4 MB  [8][128][2048]
    f16_t* attnb = (f16_t*)(ws + 124 * MB);   // 16 MB  [2048][4096]

    // 1. convert x; transpose-convert all weights (bf16 grid)
    f32_to_f16_kernel<<<S_LEN * DIM_ / 8 / 256, 256, 0, stream>>>(x, xb, S_LEN * DIM_);
    transpose_weights_kernel<<<40960, dim3(32, 8), 0, stream>>>(wq, wk, wv, wo, wqkvT, woT);

    // 2. fused QKV projection: [2048][4096] x [6144][4096]^T -> [2048][6144]
    gemm_pipe_kernel<256, 256, f16_t><<<192, 512, 0, stream>>>(
        xb, wqkvT, QKVb, S_LEN, QLD, DIM_, QLD / 256);

    // 3. RoPE Q+K in-place (Q pre-scaled); V^T transpose
    rope_qk_kernel<<<dim3(5, S_LEN), 128, 0, stream>>>(QKVb, fcos, fsin);
    transpose_f16_kernel<<<dim3(KV_DIM / 32, S_LEN / 32), dim3(32, 8), 0, stream>>>(
        QKVb + 5120, Vt, QLD, S_LEN);

    // 4. causal flash attention
    attn_kernel<<<512, 512, 0, stream>>>(QKVb, Vt, attnb);

    // 5. output projection (fp32 out): 256x128 tiles -> 256 blocks
    gemm_pipe_kernel<256, 128, float><<<256, 512, 0, stream>>>(
        attnb, woT, out, S_LEN, DIM_, DIM_, DIM_ / 128);
}